// Round 11
// baseline (589.967 us; speedup 1.0000x reference)
//
#include <hip/hip_runtime.h>
#include <stdint.h>

#define NB 4096      // batch
#define NK 64        // neighbors
#define ND 128       // dim
#define NH 4         // heads
#define ES 136       // bf16 LDS row stride (ushorts): 272B, 16B-aligned rows
#define ESW (ES/2)   // 68 dwords per row
#define MR 16        // row tile for mlp/final kernels
#define GS 392       // gate tile row stride (ushorts)
#define SFS 132      // sf fp32 row stride

typedef __attribute__((ext_vector_type(8))) short bf16x8;
typedef __attribute__((ext_vector_type(4))) float f32x4;

__device__ __forceinline__ float seluf(float x) {
    float e = 1.6732632423543772f * (__expf(x) - 1.f);
    return 1.0507009873554805f * (x > 0.f ? x : e);
}
__device__ __forceinline__ float sigmoidf_(float x) {
    return __fdividef(1.f, 1.f + __expf(-x));
}
__device__ __forceinline__ uint32_t f2bf2(float a, float b) {
    uint32_t ua = __float_as_uint(a); ua += 0x7fffu + ((ua >> 16) & 1u);
    uint32_t ub = __float_as_uint(b); ub += 0x7fffu + ((ub >> 16) & 1u);
    return (ua >> 16) | (ub & 0xffff0000u);
}
__device__ __forceinline__ uint16_t bf1(float v) {
    uint32_t u = __float_as_uint(v); u += 0x7fffu + ((u >> 16) & 1u);
    return (uint16_t)(u >> 16);
}
__device__ __forceinline__ float bflo(uint32_t v) { return __uint_as_float(v << 16); }
__device__ __forceinline__ float bfhi(uint32_t v) { return __uint_as_float(v & 0xffff0000u); }

// ------------------------------------------------- prep: bf16 K-major weight transposes
__global__ __launch_bounds__(256)
void k_prep(const float* __restrict__ att1_w, const float* __restrict__ att2_w,
            const float* __restrict__ in_w, const float* __restrict__ out_w,
            const float* __restrict__ gate_w,
            uint16_t* __restrict__ wt1, uint16_t* __restrict__ wt2,
            uint16_t* __restrict__ wt_in, uint16_t* __restrict__ wt_out,
            uint16_t* __restrict__ wt_gate)
{
    const int bx = blockIdx.x;
    const int t = threadIdx.x;
    if (bx < 64) {
        const int h = bx >> 4;
        const int q = bx & 15;
        {
            int n = t >> 1, kh = t & 1;
            for (int k0 = q * 4; k0 < q * 4 + 4; ++k0) {
                int k = k0 * 2 + kh;
                float v = att1_w[(size_t)h * 32768 + (size_t)k * ND + n];
                float vo = __shfl_xor(v, 1, 64);
                if (kh == 0)
                    ((uint32_t*)wt1)[((size_t)h * ND + n) * 64 + k0] = f2bf2(v, vo);
            }
        }
        {
            int c = t & 31, dh = t >> 5;
            int d0 = q;
            int d = d0 * 8 + dh;
            float v = att2_w[(size_t)h * 4096 + (size_t)d * 32 + c];
            float vo = __shfl_xor(v, 32, 64);
            if ((dh & 1) == 0)
                ((uint32_t*)wt2)[((size_t)h * 32 + c) * 64 + d0 * 4 + (dh >> 1)] = f2bf2(v, vo);
        }
    } else if (bx < 72) {
        int n0 = (bx - 64) * 16;
        for (int n = n0; n < n0 + 16; ++n)
            for (int k = t; k < ND; k += 256)
                wt_in[n * ND + k] = bf1(in_w[(size_t)k * ND + n]);
    } else if (bx < 80) {
        int n0 = (bx - 72) * 16;
        for (int n = n0; n < n0 + 16; ++n)
            for (int k = t; k < ND; k += 256)
                wt_out[n * ND + k] = bf1(out_w[(size_t)k * ND + n]);
    } else {
        int n0 = (bx - 80) * 16;
        for (int n = n0; n < n0 + 16; ++n)
            for (int k = t; k < 384; k += 256)
                wt_gate[n * 384 + k] = bf1(gate_w[(size_t)k * ND + n]);
    }
}

// ---------------------------------------------------------------- kernel 1
// Barriers: 1 (gather) + per head {C: s1 transpose, D: sc gather} = 9 total.
// Everything else is wave-private (redundant entmax/pool, register uproj).
__global__ __launch_bounds__(256, 4)
void k_att(const int* __restrict__ nodes, const int* __restrict__ neighbors,
           const float* __restrict__ u2e,
           const float* __restrict__ att1_w, const float* __restrict__ att1_b,
           const float* __restrict__ att2_b,
           const float* __restrict__ att3_w, const float* __restrict__ att3_b,
           const float* __restrict__ lin1_w, const float* __restrict__ lin1_b,
           const uint16_t* __restrict__ wt1, const uint16_t* __restrict__ wt2,
           float* __restrict__ hist_out,
           float* __restrict__ sums, float* __restrict__ sumsq)
{
    __shared__ alignas(16) uint16_t e_sh[NK * ES];   // normalized neighbor embeds, bf16
    __shared__ alignas(16) uint16_t s1_sh[NK * ES];  // att1 output, bf16
    __shared__ float alpha_sh[NH * NK];              // all heads precomputed
    __shared__ float sc_sh[NK];
    __shared__ float att_str[4 * NK];                // wave-private att copies
    __shared__ float u_str[4 * ND];                  // wave-private u copies

    const int b = blockIdx.x;
    const int t = threadIdx.x;
    const int lane = t & 63;
    const int wave = t >> 6;
    const int lh = lane & 15;   // fragment row/col-in-tile
    const int lg = lane >> 4;   // k-group

    // ---- gather neighbors + l2norm into LDS (bf16) ----
    for (int k = wave; k < NK; k += 4) {
        int idx = neighbors[b * NK + k];
        float2 v = ((const float2*)(u2e + (size_t)idx * ND))[lane];
        float ss = v.x * v.x + v.y * v.y;
        #pragma unroll
        for (int m = 1; m < 64; m <<= 1) ss += __shfl_xor(ss, m, 64);
        float r = 1.0f / fmaxf(sqrtf(ss), 1e-12f);
        ((uint32_t*)e_sh)[k * ESW + lane] = f2bf2(v.x * r, v.y * r);
    }
    // per-wave u copy (redundant, L1-cached)
    float2 uv = ((const float2*)(u2e + (size_t)nodes[b] * ND))[lane];
    float px = uv.x, py = uv.y;           // lane owns dims {2*lane, 2*lane+1}
    ((float2*)(u_str + wave * ND))[lane] = uv;
    float hx = 0.f, hy = 0.f;             // hist accumulator (per-wave redundant)
    __syncthreads();                                   // gather fence

    // ---- alpha for ALL heads (wave h computes head h); fenced by head-0 C/D ----
    {
        const float* lw = lin1_w + wave * ND;
        float lb = lin1_b[wave];
        #pragma unroll
        for (int it = 0; it < 4; ++it) {
            int k = it * 16 + (lane >> 2);
            int qd = lane & 3;
            const uint32_t* er = (const uint32_t*)e_sh + k * ESW + qd * 16;
            const float* lr = lw + qd * 32;
            float ap = 0.f;
            #pragma unroll 8
            for (int j2 = 0; j2 < 16; ++j2) {
                uint32_t v = er[j2];
                ap += bflo(v) * lr[2 * j2] + bfhi(v) * lr[2 * j2 + 1];
            }
            ap += __shfl_xor(ap, 1, 64);
            ap += __shfl_xor(ap, 2, 64);
            if (qd == 0)
                alpha_sh[wave * NK + k] = sigmoidf_(ap + lb) + 1.0f;
        }
    }

    for (int h = 0; h < NH; ++h) {
        // ---- per-wave rnorm of u (register-only) ----
        float rnorm;
        {
            float ss = px * px + py * py;
            #pragma unroll
            for (int m = 1; m < 64; m <<= 1) ss += __shfl_xor(ss, m, 64);
            rnorm = 1.0f / fmaxf(sqrtf(ss), 1e-12f);
        }
        // ---- per-wave uproj: wave w computes up[] at cols [32w,32w+32) ----
        float up0, up1;
        {
            int dl = lane & 31, jh = lane >> 5;
            const float* wb = att1_w + (size_t)h * 32768
                            + (size_t)(ND + jh * 64) * ND + wave * 32 + dl;
            const float* us = u_str + wave * ND + jh * 64;
            float p = 0.f;
            #pragma unroll 8
            for (int j = 0; j < 64; ++j)
                p += us[j] * wb[(size_t)j * ND];
            p += __shfl_xor(p, 32, 64);
            float upfull = p * rnorm + att1_b[h * ND + wave * 32 + dl];
            up0 = __shfl(upfull, lh, 64);
            up1 = __shfl(upfull, lh + 16, 64);
        }

        // ---- att1 via MFMA: wave owns cols [32w,32w+32); B in regs, reused x4 ----
        {
            const uint16_t* WB = wt1 + ((size_t)h * ND + wave * 32) * ND;
            bf16x8 B[4][2];
            #pragma unroll
            for (int kk = 0; kk < 4; ++kk)
                #pragma unroll
                for (int nt = 0; nt < 2; ++nt)
                    B[kk][nt] = *(const bf16x8*)(WB + (nt * 16 + lh) * ND + kk * 32 + lg * 8);
            f32x4 z = {0.f, 0.f, 0.f, 0.f};
            f32x4 acc[4][2] = {{z, z}, {z, z}, {z, z}, {z, z}};
            #pragma unroll
            for (int mt = 0; mt < 4; ++mt) {
                #pragma unroll
                for (int kk = 0; kk < 4; ++kk) {
                    bf16x8 A = *(const bf16x8*)(e_sh + (mt * 16 + lh) * ES + kk * 32 + lg * 8);
                    acc[mt][0] = __builtin_amdgcn_mfma_f32_16x16x32_bf16(A, B[kk][0], acc[mt][0], 0, 0, 0);
                    acc[mt][1] = __builtin_amdgcn_mfma_f32_16x16x32_bf16(A, B[kk][1], acc[mt][1], 0, 0, 0);
                }
            }
            #pragma unroll
            for (int mt = 0; mt < 4; ++mt)
                #pragma unroll
                for (int nt = 0; nt < 2; ++nt) {
                    float upv = nt ? up1 : up0;
                    #pragma unroll
                    for (int r = 0; r < 4; ++r) {
                        float v = seluf(acc[mt][nt][r] + upv);
                        s1_sh[(mt * 16 + lg * 4 + r) * ES + wave * 32 + nt * 16 + lh] = bf1(v);
                    }
                }
        }
        __syncthreads();                               // C (att1 cols -> att2 rows)

        // ---- att2 via MFMA: wave owns rows [16w,16w+16); then selu+att3 dot ----
        {
            const uint16_t* WB2 = wt2 + (size_t)h * 32 * ND;
            bf16x8 B2[4][2];
            #pragma unroll
            for (int kk = 0; kk < 4; ++kk)
                #pragma unroll
                for (int nt = 0; nt < 2; ++nt)
                    B2[kk][nt] = *(const bf16x8*)(WB2 + (nt * 16 + lh) * ND + kk * 32 + lg * 8);
            f32x4 z = {0.f, 0.f, 0.f, 0.f};
            f32x4 acc2[2] = {z, z};
            #pragma unroll
            for (int kk = 0; kk < 4; ++kk) {
                bf16x8 A = *(const bf16x8*)(s1_sh + (wave * 16 + lh) * ES + kk * 32 + lg * 8);
                acc2[0] = __builtin_amdgcn_mfma_f32_16x16x32_bf16(A, B2[kk][0], acc2[0], 0, 0, 0);
                acc2[1] = __builtin_amdgcn_mfma_f32_16x16x32_bf16(A, B2[kk][1], acc2[1], 0, 0, 0);
            }
            float w3a = att3_w[h * 32 + lh],      b2a = att2_b[h * 32 + lh];
            float w3b = att3_w[h * 32 + 16 + lh], b2b = att2_b[h * 32 + 16 + lh];
            float b3 = att3_b[h];
            #pragma unroll
            for (int r = 0; r < 4; ++r) {
                float v = seluf(acc2[0][r] + b2a) * w3a + seluf(acc2[1][r] + b2b) * w3b;
                v += __shfl_xor(v, 1, 64);
                v += __shfl_xor(v, 2, 64);
                v += __shfl_xor(v, 4, 64);
                v += __shfl_xor(v, 8, 64);
                if (lh == 0)
                    sc_sh[wave * 16 + lg * 4 + r] = v + b3;
            }
        }
        __syncthreads();                               // D (sc gather)

        // ---- entmax: ALL waves compute redundantly (deterministic) ----
        {
            float x   = sc_sh[lane];
            float am1 = alpha_sh[h * NK + lane] - 1.0f;
            float q   = 1.0f / am1;
            float em1 = q - 1.0f;
            float xs  = x * am1;
            float mx = xs;
            #pragma unroll
            for (int m = 1; m < 64; m <<= 1) mx = fmaxf(mx, __shfl_xor(mx, m, 64));
            float tau = mx - 1.0f;
            for (int it = 0; it < 6; ++it) {
                float tt = xs - tau;
                bool pos = tt > 0.f;
                float lgn = __logf(pos ? tt : 1.f);
                float p  = pos ? __expf(q * lgn) : 0.f;
                float dp = pos ? q * __expf(em1 * lgn) : 0.f;
                float s0 = p, s1 = dp;
                #pragma unroll
                for (int m = 1; m < 64; m <<= 1) {
                    s0 += __shfl_xor(s0, m, 64);
                    s1 += __shfl_xor(s1, m, 64);
                }
                tau += __fdividef(s0 - 1.0f, fmaxf(s1, 1e-30f));
                tau = fminf(tau, mx - 1e-6f);
            }
            float tt = xs - tau;
            bool pos = tt > 0.f;
            float p = pos ? __expf(q * __logf(pos ? tt : 1.f)) : 0.f;
            float s0 = p;
            #pragma unroll
            for (int m = 1; m < 64; m <<= 1) s0 += __shfl_xor(s0, m, 64);
            att_str[wave * NK + lane] = __fdividef(p, s0);  // wave-private, no barrier
        }

        // ---- pool: full per-wave redundant; u stays wave-private ----
        {
            const uint32_t* E = (const uint32_t*)e_sh;
            const float* as = att_str + wave * NK;
            float nx = 0.f, ny = 0.f;
            #pragma unroll 8
            for (int k = 0; k < NK; ++k) {
                uint32_t v = E[k * ESW + lane];
                float a = as[k];
                nx += bflo(v) * a;
                ny += bfhi(v) * a;
            }
            px = nx; py = ny;
            ((float2*)(u_str + wave * ND))[lane] = make_float2(px, py);
            hx += px; hy += py;
        }
        // no barrier: next head's state is wave-private (C fences s1 reuse)
    }
    if (wave == 0) {
        float hvx = hx * 0.25f, hvy = hy * 0.25f;
        ((float2*)(hist_out + (size_t)b * ND))[lane] = make_float2(hvx, hvy);
        atomicAdd(&sums[2 * lane], hvx);
        atomicAdd(&sums[2 * lane + 1], hvy);
        atomicAdd(&sumsq[2 * lane], hvx * hvx);
        atomicAdd(&sumsq[2 * lane + 1], hvy * hvy);
    }
}

// ---------------------------------------------------------------- h1 = selu(bn(hist)@in_w+b) via MFMA, fused h1 stats
__global__ __launch_bounds__(256)
void k_mlp1(const float* __restrict__ hist,
            const float* __restrict__ sums, const float* __restrict__ sumsq,
            const float* __restrict__ bn_g, const float* __restrict__ bn_b,
            const uint16_t* __restrict__ wt_in, const float* __restrict__ in_b,
            uint16_t* __restrict__ h1b,
            float* __restrict__ sums1, float* __restrict__ sumsq1)
{
    __shared__ alignas(16) uint16_t xh[MR * ES];
    const int t = threadIdx.x;
    const int lane = t & 63;
    const int wave = t >> 6;
    const int lh = lane & 15;
    const int lg = lane >> 4;
    const int row0 = blockIdx.x * MR;

    #pragma unroll
    for (int it = 0; it < 4; ++it) {
        int pos = t + it * 256;
        int r = pos >> 6, d2 = pos & 63;
        int d0 = d2 * 2;
        float m0 = sums[d0] * (1.f / 4096.f);
        float v0 = sumsq[d0] * (1.f / 4096.f) - m0 * m0;
        float sc0 = bn_g[d0] * rsqrtf(v0 + 1e-5f);
        float sh0 = bn_b[d0] - m0 * sc0;
        float m1 = sums[d0 + 1] * (1.f / 4096.f);
        float v1 = sumsq[d0 + 1] * (1.f / 4096.f) - m1 * m1;
        float sc1 = bn_g[d0 + 1] * rsqrtf(v1 + 1e-5f);
        float sh1 = bn_b[d0 + 1] - m1 * sc1;
        float2 hv = *(const float2*)(hist + (size_t)(row0 + r) * ND + d0);
        ((uint32_t*)xh)[r * ESW + d2] = f2bf2(hv.x * sc0 + sh0, hv.y * sc1 + sh1);
    }
    __syncthreads();

    const uint16_t* WB = wt_in + (size_t)(wave * 32) * ND;
    bf16x8 B[4][2];
    #pragma unroll
    for (int kk = 0; kk < 4; ++kk)
        #pragma unroll
        for (int nt = 0; nt < 2; ++nt)
            B[kk][nt] = *(const bf16x8*)(WB + (nt * 16 + lh) * ND + kk * 32 + lg * 8);
    f32x4 z = {0.f, 0.f, 0.f, 0.f};
    f32x4 acc[2] = {z, z};
    #pragma unroll
    for (int kk = 0; kk < 4; ++kk) {
        bf16x8 A = *(const bf16x8*)(xh + lh * ES + kk * 32 + lg * 8);
        acc[0] = __builtin_amdgcn_mfma_f32_16x16x32_bf16(A, B[kk][0], acc[0], 0, 0, 0);
        acc[1] = __builtin_amdgcn_mfma_f32_16x16x32_bf16(A, B[kk][1], acc[1], 0, 0, 0);
    }
    #pragma unroll
    for (int nt = 0; nt < 2; ++nt) {
        int col = wave * 32 + nt * 16 + lh;
        float bia = in_b[col];
        float s = 0.f, q = 0.f;
        #pragma unroll
        for (int r = 0; r < 4; ++r) {
            int row = lg * 4 + r;
            float hv = seluf(acc[nt][r] + bia);
            h1b[(size_t)(row0 + row) * ND + col] = bf1(hv);
            s += hv; q += hv * hv;
        }
        s += __shfl_xor(s, 16, 64); s += __shfl_xor(s, 32, 64);
        q += __shfl_xor(q, 16, 64); q += __shfl_xor(q, 32, 64);
        if (lg == 0) {
            atomicAdd(&sums1[col], s);
            atomicAdd(&sumsq1[col], q);
        }
    }
}

// ---------------------------------------------------------------- final via MFMA: neigh + gated combine
__global__ __launch_bounds__(256)
void k_final(const uint16_t* __restrict__ h1b,
             const float* __restrict__ sums1, const float* __restrict__ sumsq1,
             const float* __restrict__ bn1_g, const float* __restrict__ bn1_b,
             const uint16_t* __restrict__ wt_out, const float* __restrict__ out_b,
             const uint16_t* __restrict__ wt_gate, const float* __restrict__ gate_b,
             const int* __restrict__ nodes, const float* __restrict__ u2e,
             float* __restrict__ out)
{
    __shared__ alignas(16) uint16_t xh[MR * ES];
    __shared__ float sff[MR * SFS];
    __shared__ alignas(16) uint16_t gtile[MR * GS];
    const int t = threadIdx.x;
    const int lane = t & 63;
    const int wave = t >> 6;
    const int lh = lane & 15;
    const int lg = lane >> 4;
    const int row0 = blockIdx.x * MR;

    #pragma unroll
    for (int it = 0; it < 4; ++it) {
        int pos = t + it * 256;
        int r = pos >> 6, d2 = pos & 63;
        int d0 = d2 * 2;
        float m0 = sums1[d0] * (1.f / 4096.f);
        float v0 = sumsq1[d0] * (1.f / 4096.f) - m0 * m0;
        float sc0 = bn1_g[d0] * rsqrtf(v0 + 1e-5f);
        float sh0 = bn1_b[d0] - m0 * sc0;
        float m1 = sums1[d0 + 1] * (1.f / 4096.f);
        float v1 = sumsq1[d0 + 1] * (1.f / 4096.f) - m1 * m1;
        float sc1 = bn1_g[d0 + 1] * rsqrtf(v1 + 1e-5f);
        float sh1 = bn1_b[d0 + 1] - m1 * sc1;
        uint32_t hw = ((const uint32_t*)h1b)[(size_t)(row0 + r) * 64 + d2];
        ((uint32_t*)xh)[r * ESW + d2] = f2bf2(bflo(hw) * sc0 + sh0, bfhi(hw) * sc1 + sh1);
        float2 sv = *(const float2*)(u2e + (size_t)nodes[row0 + r] * ND + d0);
        sff[r * SFS + d0]     = sv.x;
        sff[r * SFS + d0 + 1] = sv.y;
        ((uint32_t*)gtile)[r * (GS / 2) + d2] = f2bf2(sv.x, sv.y);
    }
    __syncthreads();

    f32x4 z = {0.f, 0.f, 0.f, 0.f};
    f32x4 accN[2] = {z, z};
    {
        const uint16_t* WB = wt_out + (size_t)(wave * 32) * ND;
        bf16x8 B[4][2];
        #pragma unroll
        for (int kk = 0; kk < 4; ++kk)
            #pragma unroll
            for (int nt = 0; nt < 2; ++nt)
                B[kk][nt] = *(const bf16x8*)(WB + (nt * 16 + lh) * ND + kk * 32 + lg * 8);
        #pragma unroll
        for (int kk = 0; kk < 4; ++kk) {
            bf16x8 A = *(const bf16x8*)(xh + lh * ES + kk * 32 + lg * 8);
            accN[0] = __builtin_amdgcn_mfma_f32_16x16x32_bf16(A, B[kk][0], accN[0], 0, 0, 0);
            accN[1] = __builtin_amdgcn_mfma_f32_16x16x32_bf16(A, B[kk][1], accN[1], 0, 0, 0);
        }
    }
    #pragma unroll
    for (int nt = 0; nt < 2; ++nt) {
        int col = wave * 32 + nt * 16 + lh;
        float bia = out_b[col];
        #pragma unroll
        for (int r = 0; r < 4; ++r) {
            int row = lg * 4 + r;
            float n = accN[nt][r] + bia;
            float s = sff[row * SFS + col];
            gtile[row * GS + 128 + col] = bf1(n);
            gtile[row * GS + 256 + col] = bf1(s * n);
        }
    }
    __syncthreads();

    f32x4 accG[2] = {z, z};
    #pragma unroll
    for (int kk = 0; kk < 12; ++kk) {
        bf16x8 A = *(const bf16x8*)(gtile + lh * GS + kk * 32 + lg * 8);
        #pragma unroll
        for (int nt = 0; nt < 2; ++nt) {
            bf16x8 Bf = *(const bf16x8*)(wt_gate + (size_t)(wave * 32 + nt * 16 + lh) * 384 + kk * 32 + lg * 8);
            accG[nt] = __builtin_amdgcn_mfma_f32_16x16x32_bf16(A, Bf, accG[nt], 0, 0, 0);
        }
    }
    #pragma unroll
    for (int nt = 0; nt < 2; ++nt) {
        int col = wave * 32 + nt * 16 + lh;
        float gb = gate_b[col];
        float ob = out_b[col];
        #pragma unroll
        for (int r = 0; r < 4; ++r) {
            int row = lg * 4 + r;
            float gama = sigmoidf_(accG[nt][r] + gb);
            float s = sff[row * SFS + col];
            float n = accN[nt][r] + ob;
            out[(size_t)(row0 + row) * ND + col] = gama * s + (1.f - gama) * n;
        }
    }
}

// ---------------------------------------------------------------- launch
extern "C" void kernel_launch(void* const* d_in, const int* in_sizes, int n_in,
                              void* d_out, int out_size, void* d_ws, size_t ws_size,
                              hipStream_t stream)
{
    const int*   nodes     = (const int*)d_in[0];
    const int*   neighbors = (const int*)d_in[1];
    const float* u2e       = (const float*)d_in[2];
    const float* att1_w    = (const float*)d_in[3];
    const float* att1_b    = (const float*)d_in[4];
    const float* att2_w    = (const float*)d_in[5];
    const float* att2_b    = (const float*)d_in[6];
    const float* att3_w    = (const float*)d_in[7];
    const float* att3_b    = (const float*)d_in[8];
    const float* lin1_w    = (const float*)d_in[9];
    const float* lin1_b    = (const float*)d_in[10];
    const float* gate_w    = (const float*)d_in[11];
    const float* gate_b    = (const float*)d_in[12];
    const float* bn_g      = (const float*)d_in[13];
    const float* bn_b      = (const float*)d_in[14];
    const float* bn1_g     = (const float*)d_in[15];
    const float* bn1_b     = (const float*)d_in[16];
    const float* in_w      = (const float*)d_in[17];
    const float* in_b      = (const float*)d_in[18];
    const float* out_w     = (const float*)d_in[19];
    const float* out_b     = (const float*)d_in[20];
    float* out = (float*)d_out;

    float* ws      = (float*)d_ws;
    float* g_hist  = ws;                                   // 4096*128 f32
    float* st      = ws + (size_t)NB * ND;                 // 512 f32 stats
    uint16_t* wt1  = (uint16_t*)(st + 512);                // 4*128*128 bf16
    uint16_t* wt2  = wt1 + (size_t)NH * ND * ND;           // 4*32*128
    uint16_t* wt_in   = wt2 + (size_t)NH * 32 * ND;        // 128*128
    uint16_t* wt_out  = wt_in + (size_t)ND * ND;           // 128*128
    uint16_t* wt_gate = wt_out + (size_t)ND * ND;          // 128*384
    uint16_t* h1b     = wt_gate + (size_t)ND * 384;        // 4096*128 bf16

    (void)hipMemsetAsync(st, 0, 512 * sizeof(float), stream);

    k_prep<<<88, 256, 0, stream>>>(att1_w, att2_w, in_w, out_w, gate_w,
                                   wt1, wt2, wt_in, wt_out, wt_gate);
    k_att<<<NB, 256, 0, stream>>>(nodes, neighbors, u2e,
                                  att1_w, att1_b, att2_b,
                                  att3_w, att3_b, lin1_w, lin1_b,
                                  wt1, wt2,
                                  g_hist, st, st + 128);
    k_mlp1<<<NB / MR, 256, 0, stream>>>(g_hist, st, st + 128, bn_g, bn_b,
                                        wt_in, in_b, h1b, st + 256, st + 384);
    k_final<<<NB / MR, 256, 0, stream>>>(h1b, st + 256, st + 384, bn1_g, bn1_b,
                                         wt_out, out_b, wt_gate, gate_b,
                                         nodes, u2e, out);
}